// Round 1
// baseline (4076.591 us; speedup 1.0000x reference)
//
#include <hip/hip_runtime.h>
#include <hip/hip_bf16.h>
#include <cstddef>
#include <math.h>

#define kB 32
#define kN1 4096
#define kS1 512
#define kNS1 32
#define kS2 128
#define kNS2 64

// ---------------- weight folding: W' = W * g/sqrt(1+eps), b' = b*g/sqrt(1+eps) + bt ----------
__global__ void fold_kernel(const float* __restrict__ W, const float* __restrict__ bias,
                            const float* __restrict__ g, const float* __restrict__ bt,
                            int O, int K, int Kp,
                            float* __restrict__ Wf, float* __restrict__ WT,
                            float* __restrict__ bf) {
  float inv = 1.0f / sqrtf(1.0f + 1e-5f);
  int stride = gridDim.x * blockDim.x;
  int tid = blockIdx.x * blockDim.x + threadIdx.x;
  for (int i = tid; i < O * Kp; i += stride) {
    int o = i / Kp, k = i - o * Kp;
    float s = g[o] * inv;
    float w = (k < K) ? W[o * K + k] * s : 0.0f;
    if (Wf) Wf[o * Kp + k] = w;
    if (WT) WT[k * O + o] = w;
  }
  for (int o = tid; o < O; o += stride) {
    bf[o] = bias[o] * (g[o] * inv) + bt[o];
  }
}

// ---------------- farthest point sampling ----------------
// One block per batch. Coords in LDS (SoA), per-thread dist in registers.
// Matches reference: idxs[0]=0; then 511 rounds of (update min-dist, first-argmax).
template <int N, int NP, int T>
__global__ __launch_bounds__(T) void fps_kernel(const float* __restrict__ xyz,  // (B,3,N)
                                                float* __restrict__ nx) {       // (B,3,NP)
  __shared__ float xs[N], ys[N], zs[N];
  __shared__ float sval[T / 64];
  __shared__ int sidx[T / 64];
  __shared__ int fid[NP];
  constexpr int R = N / T;
  int b = blockIdx.x, t = threadIdx.x;
  const float* base = xyz + (size_t)b * 3 * N;
  float dreg[R];
#pragma unroll
  for (int r = 0; r < R; ++r) {
    int i = t + r * T;
    xs[i] = base[i];
    ys[i] = base[N + i];
    zs[i] = base[2 * N + i];
    dreg[r] = 1e10f;
  }
  if (t == 0) fid[0] = 0;
  __syncthreads();
  int far = 0;
  for (int it = 1; it < NP; ++it) {
    float cx = xs[far], cy = ys[far], cz = zs[far];
    float best = -1.0f;
    int bi = 0;
#pragma unroll
    for (int r = 0; r < R; ++r) {
      int i = t + r * T;
      float dx = __fsub_rn(xs[i], cx);
      float dy = __fsub_rn(ys[i], cy);
      float dz = __fsub_rn(zs[i], cz);
      float d = fmaf(dz, dz, fmaf(dy, dy, __fmul_rn(dx, dx)));
      float nd = fminf(dreg[r], d);
      dreg[r] = nd;
      if (nd > best) { best = nd; bi = i; }   // ascending i per thread -> first max kept
    }
#pragma unroll
    for (int off = 32; off >= 1; off >>= 1) {
      float ov = __shfl_xor(best, off, 64);
      int oi = __shfl_xor(bi, off, 64);
      if (ov > best || (ov == best && oi < bi)) { best = ov; bi = oi; }
    }
    if ((t & 63) == 0) { sval[t >> 6] = best; sidx[t >> 6] = bi; }
    __syncthreads();
    best = sval[0]; bi = sidx[0];
#pragma unroll
    for (int w = 1; w < T / 64; ++w) {
      float ov = sval[w];
      int oi = sidx[w];
      if (ov > best || (ov == best && oi < bi)) { best = ov; bi = oi; }
    }
    far = bi;
    if (t == 0) fid[it] = far;
    __syncthreads();
  }
  for (int s = t; s < NP; s += T) {
    int f = fid[s];
    nx[(size_t)b * 3 * NP + s] = xs[f];
    nx[(size_t)b * 3 * NP + NP + s] = ys[f];
    nx[(size_t)b * 3 * NP + 2 * NP + s] = zs[f];
  }
}

// ---------------- ball query: first NS indices (ascending) with sqr <= r^2; pad with first ----
template <int NPTS, int NQ, int NS>
__global__ void bq_kernel(const float* __restrict__ pts, const float* __restrict__ qry,
                          float r2, int* __restrict__ gidx) {
  int gw = (blockIdx.x * blockDim.x + threadIdx.x) >> 6;
  int lane = threadIdx.x & 63;
  if (gw >= kB * NQ) return;
  int b = gw / NQ, s = gw - b * NQ;
  const float* pb = pts + (size_t)b * 3 * NPTS;
  float cx = qry[(size_t)b * 3 * NQ + s];
  float cy = qry[(size_t)b * 3 * NQ + NQ + s];
  float cz = qry[(size_t)b * 3 * NQ + 2 * NQ + s];
  float ss = fmaf(cz, cz, fmaf(cy, cy, __fmul_rn(cx, cx)));
  int* out = gidx + (size_t)gw * NS;
  int have = 0, first = 0;
  bool gotfirst = false;
  for (int n0 = 0; n0 < NPTS; n0 += 64) {
    int n = n0 + lane;
    float x = pb[n], y = pb[NPTS + n], z = pb[2 * NPTS + n];
    float dd = fmaf(z, z, fmaf(y, y, __fmul_rn(x, x)));
    float cross = fmaf(cz, z, fmaf(cy, y, __fmul_rn(cx, x)));
    float sqr = __fsub_rn(__fadd_rn(ss, dd), __fmul_rn(2.0f, cross));
    bool pred = !(sqr > r2);
    unsigned long long mask = __ballot(pred);
    if (!gotfirst && mask) { first = n0 + (__ffsll(mask) - 1); gotfirst = true; }
    if (pred) {
      int pos = have + __popcll(mask & ((1ull << lane) - 1ull));
      if (pos < NS) out[pos] = n;
    }
    have += __popcll(mask);
    if (have >= NS) break;
  }
  for (int slot = have + lane; slot < NS; slot += 64) out[slot] = first;
}

// ---------------- SA1 grouped MLP (3->64->64->128) + max over 32 samples ----------------
// Half-wave (32 lanes) per query; lane = sample. Weights staged in LDS.
__global__ __launch_bounds__(256, 2) void sa1_mlp_kernel(
    const float* __restrict__ xyz, const float* __restrict__ nx1,
    const int* __restrict__ gidx,
    const float* __restrict__ W0f, const float* __restrict__ bf0,
    const float* __restrict__ W1f, const float* __restrict__ bf1,
    const float* __restrict__ WT2, const float* __restrict__ bf2,
    float* __restrict__ l1_pts) {
  __shared__ float sW0[64 * 4], sb0[64], sW1[64 * 64], sb1[64], sWT2[64 * 128], sb2[128];
  int t = threadIdx.x;
  for (int i = t; i < 64 * 4; i += 256) sW0[i] = W0f[i];
  for (int i = t; i < 64 * 64; i += 256) sW1[i] = W1f[i];
  for (int i = t; i < 64 * 128; i += 256) sWT2[i] = WT2[i];
  if (t < 64) { sb0[t] = bf0[t]; sb1[t] = bf1[t]; }
  if (t < 128) sb2[t] = bf2[t];
  __syncthreads();
  int q = blockIdx.x * 8 + (t >> 5);
  int lane5 = t & 31;
  int b = q >> 9, s = q & 511;
  int idx = gidx[(size_t)q * kNS1 + lane5];
  float cx = nx1[(size_t)b * 3 * kS1 + s];
  float cy = nx1[(size_t)b * 3 * kS1 + kS1 + s];
  float cz = nx1[(size_t)b * 3 * kS1 + 2 * kS1 + s];
  const float* pb = xyz + (size_t)b * 3 * kN1;
  float f0 = pb[idx] - cx, f1 = pb[kN1 + idx] - cy, f2 = pb[2 * kN1 + idx] - cz;
  float X1[64];
#pragma unroll
  for (int o = 0; o < 64; ++o) {
    float v = fmaf(f2, sW0[o * 4 + 2], fmaf(f1, sW0[o * 4 + 1], fmaf(f0, sW0[o * 4], sb0[o])));
    X1[o] = fmaxf(v, 0.0f);
  }
  float Z[128];
#pragma unroll
  for (int j = 0; j < 128; ++j) Z[j] = sb2[j];
  for (int o = 0; o < 64; ++o) {   // fused layer2 -> layer3
    float acc = sb1[o];
#pragma unroll
    for (int k = 0; k < 64; k += 4) {
      float4 w = *(const float4*)&sW1[o * 64 + k];
      acc = fmaf(X1[k], w.x, acc);
      acc = fmaf(X1[k + 1], w.y, acc);
      acc = fmaf(X1[k + 2], w.z, acc);
      acc = fmaf(X1[k + 3], w.w, acc);
    }
    float y = fmaxf(acc, 0.0f);
#pragma unroll
    for (int j = 0; j < 128; j += 4) {
      float4 w = *(const float4*)&sWT2[o * 128 + j];
      Z[j] = fmaf(y, w.x, Z[j]);
      Z[j + 1] = fmaf(y, w.y, Z[j + 1]);
      Z[j + 2] = fmaf(y, w.z, Z[j + 2]);
      Z[j + 3] = fmaf(y, w.w, Z[j + 3]);
    }
  }
  float* outp = l1_pts + (size_t)q * 128;
#pragma unroll
  for (int j = 0; j < 128; ++j) {
    float m = fmaxf(Z[j], 0.0f);
    m = fmaxf(m, __shfl_xor(m, 16, 64));
    m = fmaxf(m, __shfl_xor(m, 8, 64));
    m = fmaxf(m, __shfl_xor(m, 4, 64));
    m = fmaxf(m, __shfl_xor(m, 2, 64));
    m = fmaxf(m, __shfl_xor(m, 1, 64));
    if (lane5 == 0) outp[j] = m;
  }
}

// ---------------- SA2 grouped MLP (131->128->128->256) + max over 64 samples ----------------
// Full wave per query; lane = sample. f[132] + X2[128] in registers (1 wave/SIMD).
__global__ __launch_bounds__(256, 1) void sa2_mlp_kernel(
    const float* __restrict__ nx1, const float* __restrict__ l1_pts,
    const float* __restrict__ nx2, const int* __restrict__ gidx2,
    const float* __restrict__ W1f, const float* __restrict__ bf1,
    const float* __restrict__ WT2, const float* __restrict__ bf2,
    const float* __restrict__ W3f, const float* __restrict__ bf3,
    float* __restrict__ l2_pts) {
  int wv = blockIdx.x * 4 + (threadIdx.x >> 6);
  int lane = threadIdx.x & 63;
  int b = wv >> 7, s = wv & 127;
  int idx = gidx2[(size_t)wv * kNS2 + lane];
  float cx = nx2[(size_t)b * 3 * kS2 + s];
  float cy = nx2[(size_t)b * 3 * kS2 + kS2 + s];
  float cz = nx2[(size_t)b * 3 * kS2 + 2 * kS2 + s];
  float f[132];
  f[0] = nx1[(size_t)b * 3 * kS1 + idx] - cx;
  f[1] = nx1[(size_t)b * 3 * kS1 + kS1 + idx] - cy;
  f[2] = nx1[(size_t)b * 3 * kS1 + 2 * kS1 + idx] - cz;
  const float* pr = l1_pts + ((size_t)b * kS1 + idx) * 128;
#pragma unroll
  for (int c = 0; c < 128; c += 4) {
    float4 v = *(const float4*)&pr[c];
    f[3 + c] = v.x; f[4 + c] = v.y; f[5 + c] = v.z; f[6 + c] = v.w;
  }
  f[131] = 0.0f;
  float X2[128];
#pragma unroll
  for (int j = 0; j < 128; ++j) X2[j] = bf2[j];
  for (int o = 0; o < 128; ++o) {   // fused layer1 -> layer2
    float acc = bf1[o];
#pragma unroll
    for (int k = 0; k < 132; k += 4) {
      float4 w = *(const float4*)&W1f[o * 132 + k];
      acc = fmaf(f[k], w.x, acc);
      acc = fmaf(f[k + 1], w.y, acc);
      acc = fmaf(f[k + 2], w.z, acc);
      acc = fmaf(f[k + 3], w.w, acc);
    }
    float y = fmaxf(acc, 0.0f);
#pragma unroll
    for (int j = 0; j < 128; j += 4) {
      float4 w = *(const float4*)&WT2[o * 128 + j];
      X2[j] = fmaf(y, w.x, X2[j]);
      X2[j + 1] = fmaf(y, w.y, X2[j + 1]);
      X2[j + 2] = fmaf(y, w.z, X2[j + 2]);
      X2[j + 3] = fmaf(y, w.w, X2[j + 3]);
    }
  }
#pragma unroll
  for (int k = 0; k < 128; ++k) X2[k] = fmaxf(X2[k], 0.0f);
  float* outp = l2_pts + (size_t)wv * 256;
  for (int j = 0; j < 256; ++j) {
    float acc = bf3[j];
#pragma unroll
    for (int k = 0; k < 128; k += 4) {
      float4 w = *(const float4*)&W3f[j * 128 + k];
      acc = fmaf(X2[k], w.x, acc);
      acc = fmaf(X2[k + 1], w.y, acc);
      acc = fmaf(X2[k + 2], w.z, acc);
      acc = fmaf(X2[k + 3], w.w, acc);
    }
    float m = fmaxf(acc, 0.0f);
    m = fmaxf(m, __shfl_xor(m, 32, 64));
    m = fmaxf(m, __shfl_xor(m, 16, 64));
    m = fmaxf(m, __shfl_xor(m, 8, 64));
    m = fmaxf(m, __shfl_xor(m, 4, 64));
    m = fmaxf(m, __shfl_xor(m, 2, 64));
    m = fmaxf(m, __shfl_xor(m, 1, 64));
    if (lane == 0) outp[j] = m;
  }
}

// ---------------- SA3 (group-all): concat -> 259->256->512->1024 -> max over 128 ----------------
__global__ void concat3_kernel(const float* __restrict__ nx2, const float* __restrict__ l2_pts,
                               float* __restrict__ F0) {
  int tot = kB * kS2 * 260;
  for (int i = blockIdx.x * blockDim.x + threadIdx.x; i < tot; i += gridDim.x * blockDim.x) {
    int row = i / 260, k = i - row * 260;
    int b = row >> 7, s = row & 127;
    float v;
    if (k < 3) v = nx2[(size_t)b * 3 * kS2 + k * kS2 + s];
    else if (k < 259) v = l2_pts[(size_t)row * 256 + (k - 3)];
    else v = 0.0f;
    F0[i] = v;
  }
}

template <int KP>
__global__ __launch_bounds__(256, 2) void mlp_pass_kernel(
    const float* __restrict__ X, const float* __restrict__ WT, const float* __restrict__ bf,
    int O, float* __restrict__ Y) {
  __shared__ float sF[16 * KP];
  int stile = blockIdx.x, t = threadIdx.x;
  int j = blockIdx.y * 256 + t;
  const float* xb = X + (size_t)stile * 16 * KP;
  for (int i = t; i < 16 * KP; i += 256) sF[i] = xb[i];
  __syncthreads();
  float acc[16];
  float bj = bf[j];
#pragma unroll
  for (int s = 0; s < 16; ++s) acc[s] = bj;
  for (int k = 0; k < KP; k += 4) {
    float w0 = WT[(size_t)k * O + j];
    float w1 = WT[(size_t)(k + 1) * O + j];
    float w2 = WT[(size_t)(k + 2) * O + j];
    float w3 = WT[(size_t)(k + 3) * O + j];
#pragma unroll
    for (int s = 0; s < 16; ++s) {
      const float4 fv = *(const float4*)&sF[s * KP + k];
      acc[s] = fmaf(fv.x, w0, acc[s]);
      acc[s] = fmaf(fv.y, w1, acc[s]);
      acc[s] = fmaf(fv.z, w2, acc[s]);
      acc[s] = fmaf(fv.w, w3, acc[s]);
    }
  }
  float* yb = Y + (size_t)stile * 16 * O + j;
#pragma unroll
  for (int s = 0; s < 16; ++s) yb[(size_t)s * O] = fmaxf(acc[s], 0.0f);
}

__global__ __launch_bounds__(256, 2) void sa3_final_kernel(
    const float* __restrict__ X2g, const float* __restrict__ WTc, const float* __restrict__ bfc,
    float* __restrict__ out) {
  __shared__ float sF[16 * 512];
  int b = blockIdx.x, t = threadIdx.x;
  int j = blockIdx.y * 256 + t;
  float m = 0.0f;
  float bj = bfc[j];
  for (int st = 0; st < 8; ++st) {
    const float* xb = X2g + ((size_t)b * 128 + st * 16) * 512;
    for (int i = t; i < 16 * 512; i += 256) sF[i] = xb[i];
    __syncthreads();
    float acc[16];
#pragma unroll
    for (int s = 0; s < 16; ++s) acc[s] = bj;
    for (int k = 0; k < 512; k += 4) {
      float w0 = WTc[(size_t)k * 1024 + j];
      float w1 = WTc[(size_t)(k + 1) * 1024 + j];
      float w2 = WTc[(size_t)(k + 2) * 1024 + j];
      float w3 = WTc[(size_t)(k + 3) * 1024 + j];
#pragma unroll
      for (int s = 0; s < 16; ++s) {
        const float4 fv = *(const float4*)&sF[s * 512 + k];
        acc[s] = fmaf(fv.x, w0, acc[s]);
        acc[s] = fmaf(fv.y, w1, acc[s]);
        acc[s] = fmaf(fv.z, w2, acc[s]);
        acc[s] = fmaf(fv.w, w3, acc[s]);
      }
    }
#pragma unroll
    for (int s = 0; s < 16; ++s) m = fmaxf(m, fmaxf(acc[s], 0.0f));
    __syncthreads();
  }
  out[(size_t)b * 1024 + j] = m;
}

// ---------------- launch ----------------
extern "C" void kernel_launch(void* const* d_in, const int* in_sizes, int n_in,
                              void* d_out, int out_size, void* d_ws, size_t ws_size,
                              hipStream_t stream) {
  (void)in_sizes; (void)n_in; (void)out_size; (void)ws_size;
  const float* xyz = (const float*)d_in[0];
  auto WP = [&](int layer, int part) -> const float* {
    return (const float*)d_in[1 + layer * 4 + part];
  };
  float* wsf = (float*)d_ws;
  size_t cur = 0;
  auto alloc = [&](size_t n) { size_t o = cur; cur += (n + 63) & ~(size_t)63; return o; };
  size_t o_nx1 = alloc((size_t)kB * 3 * kS1);
  size_t o_nx2 = alloc((size_t)kB * 3 * kS2);
  size_t o_l1pts = alloc((size_t)kB * kS1 * 128);
  size_t o_l2pts = alloc((size_t)kB * kS2 * 256);
  size_t o_F0 = alloc((size_t)kB * kS2 * 260);
  size_t o_X1g = alloc((size_t)kB * kS2 * 256);
  size_t o_X2g = alloc((size_t)kB * kS2 * 512);
  size_t o_s1w0 = alloc(64 * 4), o_s1b0 = alloc(64);
  size_t o_s1w1 = alloc(64 * 64), o_s1b1 = alloc(64);
  size_t o_s1wt2 = alloc(64 * 128), o_s1b2 = alloc(128);
  size_t o_s2w1 = alloc(128 * 132), o_s2b1 = alloc(128);
  size_t o_s2wt2 = alloc(128 * 128), o_s2b2 = alloc(128);
  size_t o_s2w3 = alloc(256 * 128), o_s2b3 = alloc(256);
  size_t o_s3wtA = alloc(260 * 256), o_s3bA = alloc(256);
  size_t o_s3wtB = alloc(256 * 512), o_s3bB = alloc(512);
  size_t o_s3wtC = alloc(512 * 1024), o_s3bC = alloc(1024);
  size_t o_gidx1 = alloc((size_t)kB * kS1 * kNS1);
  size_t o_gidx2 = alloc((size_t)kB * kS2 * kNS2);
  int* gidx1 = (int*)(wsf + o_gidx1);
  int* gidx2 = (int*)(wsf + o_gidx2);

  // fold all 9 layers
  fold_kernel<<<64, 256, 0, stream>>>(WP(0, 0), WP(0, 1), WP(0, 2), WP(0, 3), 64, 3, 4,
                                      wsf + o_s1w0, (float*)nullptr, wsf + o_s1b0);
  fold_kernel<<<64, 256, 0, stream>>>(WP(1, 0), WP(1, 1), WP(1, 2), WP(1, 3), 64, 64, 64,
                                      wsf + o_s1w1, (float*)nullptr, wsf + o_s1b1);
  fold_kernel<<<64, 256, 0, stream>>>(WP(2, 0), WP(2, 1), WP(2, 2), WP(2, 3), 128, 64, 64,
                                      (float*)nullptr, wsf + o_s1wt2, wsf + o_s1b2);
  fold_kernel<<<128, 256, 0, stream>>>(WP(3, 0), WP(3, 1), WP(3, 2), WP(3, 3), 128, 131, 132,
                                       wsf + o_s2w1, (float*)nullptr, wsf + o_s2b1);
  fold_kernel<<<128, 256, 0, stream>>>(WP(4, 0), WP(4, 1), WP(4, 2), WP(4, 3), 128, 128, 128,
                                       (float*)nullptr, wsf + o_s2wt2, wsf + o_s2b2);
  fold_kernel<<<128, 256, 0, stream>>>(WP(5, 0), WP(5, 1), WP(5, 2), WP(5, 3), 256, 128, 128,
                                       wsf + o_s2w3, (float*)nullptr, wsf + o_s2b3);
  fold_kernel<<<256, 256, 0, stream>>>(WP(6, 0), WP(6, 1), WP(6, 2), WP(6, 3), 256, 259, 260,
                                       (float*)nullptr, wsf + o_s3wtA, wsf + o_s3bA);
  fold_kernel<<<256, 256, 0, stream>>>(WP(7, 0), WP(7, 1), WP(7, 2), WP(7, 3), 512, 256, 256,
                                       (float*)nullptr, wsf + o_s3wtB, wsf + o_s3bB);
  fold_kernel<<<512, 256, 0, stream>>>(WP(8, 0), WP(8, 1), WP(8, 2), WP(8, 3), 1024, 512, 512,
                                       (float*)nullptr, wsf + o_s3wtC, wsf + o_s3bC);

  // SA1
  fps_kernel<kN1, kS1, 512><<<kB, 512, 0, stream>>>(xyz, wsf + o_nx1);
  bq_kernel<kN1, kS1, kNS1><<<(kB * kS1) / 4, 256, 0, stream>>>(xyz, wsf + o_nx1, 0.04f, gidx1);
  sa1_mlp_kernel<<<(kB * kS1) / 8, 256, 0, stream>>>(
      xyz, wsf + o_nx1, gidx1,
      wsf + o_s1w0, wsf + o_s1b0, wsf + o_s1w1, wsf + o_s1b1, wsf + o_s1wt2, wsf + o_s1b2,
      wsf + o_l1pts);

  // SA2
  fps_kernel<kS1, kS2, 128><<<kB, 128, 0, stream>>>(wsf + o_nx1, wsf + o_nx2);
  bq_kernel<kS1, kS2, kNS2><<<(kB * kS2) / 4, 256, 0, stream>>>(wsf + o_nx1, wsf + o_nx2, 0.16f, gidx2);
  sa2_mlp_kernel<<<(kB * kS2) / 4, 256, 0, stream>>>(
      wsf + o_nx1, wsf + o_l1pts, wsf + o_nx2, gidx2,
      wsf + o_s2w1, wsf + o_s2b1, wsf + o_s2wt2, wsf + o_s2b2, wsf + o_s2w3, wsf + o_s2b3,
      wsf + o_l2pts);

  // SA3 (group all)
  concat3_kernel<<<1024, 256, 0, stream>>>(wsf + o_nx2, wsf + o_l2pts, wsf + o_F0);
  mlp_pass_kernel<260><<<dim3(256, 1), 256, 0, stream>>>(wsf + o_F0, wsf + o_s3wtA, wsf + o_s3bA, 256, wsf + o_X1g);
  mlp_pass_kernel<256><<<dim3(256, 2), 256, 0, stream>>>(wsf + o_X1g, wsf + o_s3wtB, wsf + o_s3bB, 512, wsf + o_X2g);
  sa3_final_kernel<<<dim3(kB, 4), 256, 0, stream>>>(wsf + o_X2g, wsf + o_s3wtC, wsf + o_s3bC, (float*)d_out);
}

// Round 2
// 2199.231 us; speedup vs baseline: 1.8536x; 1.8536x over previous
//
#include <hip/hip_runtime.h>
#include <hip/hip_bf16.h>
#include <cstddef>
#include <math.h>

#define kB 32
#define kN1 4096
#define kS1 512
#define kNS1 32
#define kS2 128
#define kNS2 64

// ---------------- weight folding: W' = W * g/sqrt(1+eps), b' = b*g/sqrt(1+eps) + bt ----------
__global__ void fold_kernel(const float* __restrict__ W, const float* __restrict__ bias,
                            const float* __restrict__ g, const float* __restrict__ bt,
                            int O, int K, int Kp,
                            float* __restrict__ Wf, float* __restrict__ WT,
                            float* __restrict__ bf) {
  float inv = 1.0f / sqrtf(1.0f + 1e-5f);
  int stride = gridDim.x * blockDim.x;
  int tid = blockIdx.x * blockDim.x + threadIdx.x;
  for (int i = tid; i < O * Kp; i += stride) {
    int o = i / Kp, k = i - o * Kp;
    float s = g[o] * inv;
    float w = (k < K) ? W[o * K + k] * s : 0.0f;
    if (Wf) Wf[o * Kp + k] = w;
    if (WT) WT[k * O + o] = w;
  }
  for (int o = tid; o < O; o += stride) {
    bf[o] = bias[o] * (g[o] * inv) + bt[o];
  }
}

// ---------------- farthest point sampling ----------------
template <int N, int NP, int T>
__global__ __launch_bounds__(T) void fps_kernel(const float* __restrict__ xyz,  // (B,3,N)
                                                float* __restrict__ nx) {       // (B,3,NP)
  __shared__ float xs[N], ys[N], zs[N];
  __shared__ float sval[T / 64];
  __shared__ int sidx[T / 64];
  __shared__ int fid[NP];
  constexpr int R = N / T;
  int b = blockIdx.x, t = threadIdx.x;
  const float* base = xyz + (size_t)b * 3 * N;
  float dreg[R];
#pragma unroll
  for (int r = 0; r < R; ++r) {
    int i = t + r * T;
    xs[i] = base[i];
    ys[i] = base[N + i];
    zs[i] = base[2 * N + i];
    dreg[r] = 1e10f;
  }
  if (t == 0) fid[0] = 0;
  __syncthreads();
  int far = 0;
  for (int it = 1; it < NP; ++it) {
    float cx = xs[far], cy = ys[far], cz = zs[far];
    float best = -1.0f;
    int bi = 0;
#pragma unroll
    for (int r = 0; r < R; ++r) {
      int i = t + r * T;
      float dx = __fsub_rn(xs[i], cx);
      float dy = __fsub_rn(ys[i], cy);
      float dz = __fsub_rn(zs[i], cz);
      float d = fmaf(dz, dz, fmaf(dy, dy, __fmul_rn(dx, dx)));
      float nd = fminf(dreg[r], d);
      dreg[r] = nd;
      if (nd > best) { best = nd; bi = i; }
    }
#pragma unroll
    for (int off = 32; off >= 1; off >>= 1) {
      float ov = __shfl_xor(best, off, 64);
      int oi = __shfl_xor(bi, off, 64);
      if (ov > best || (ov == best && oi < bi)) { best = ov; bi = oi; }
    }
    if ((t & 63) == 0) { sval[t >> 6] = best; sidx[t >> 6] = bi; }
    __syncthreads();
    best = sval[0]; bi = sidx[0];
#pragma unroll
    for (int w = 1; w < T / 64; ++w) {
      float ov = sval[w];
      int oi = sidx[w];
      if (ov > best || (ov == best && oi < bi)) { best = ov; bi = oi; }
    }
    far = bi;
    if (t == 0) fid[it] = far;
    __syncthreads();
  }
  for (int s = t; s < NP; s += T) {
    int f = fid[s];
    nx[(size_t)b * 3 * NP + s] = xs[f];
    nx[(size_t)b * 3 * NP + NP + s] = ys[f];
    nx[(size_t)b * 3 * NP + 2 * NP + s] = zs[f];
  }
}

// ---------------- ball query ----------------
template <int NPTS, int NQ, int NS>
__global__ void bq_kernel(const float* __restrict__ pts, const float* __restrict__ qry,
                          float r2, int* __restrict__ gidx) {
  int gw = (blockIdx.x * blockDim.x + threadIdx.x) >> 6;
  int lane = threadIdx.x & 63;
  if (gw >= kB * NQ) return;
  int b = gw / NQ, s = gw - b * NQ;
  const float* pb = pts + (size_t)b * 3 * NPTS;
  float cx = qry[(size_t)b * 3 * NQ + s];
  float cy = qry[(size_t)b * 3 * NQ + NQ + s];
  float cz = qry[(size_t)b * 3 * NQ + 2 * NQ + s];
  float ss = fmaf(cz, cz, fmaf(cy, cy, __fmul_rn(cx, cx)));
  int* out = gidx + (size_t)gw * NS;
  int have = 0, first = 0;
  bool gotfirst = false;
  for (int n0 = 0; n0 < NPTS; n0 += 64) {
    int n = n0 + lane;
    float x = pb[n], y = pb[NPTS + n], z = pb[2 * NPTS + n];
    float dd = fmaf(z, z, fmaf(y, y, __fmul_rn(x, x)));
    float cross = fmaf(cz, z, fmaf(cy, y, __fmul_rn(cx, x)));
    float sqr = __fsub_rn(__fadd_rn(ss, dd), __fmul_rn(2.0f, cross));
    bool pred = !(sqr > r2);
    unsigned long long mask = __ballot(pred);
    if (!gotfirst && mask) { first = n0 + (__ffsll(mask) - 1); gotfirst = true; }
    if (pred) {
      int pos = have + __popcll(mask & ((1ull << lane) - 1ull));
      if (pos < NS) out[pos] = n;
    }
    have += __popcll(mask);
    if (have >= NS) break;
  }
  for (int slot = have + lane; slot < NS; slot += 64) out[slot] = first;
}

// ---------------- SA1 grouped MLP (3->64->64->128) + max over 32 samples ----------------
// Block = 128 threads = 4 queries x 32 samples; thread owns one row.
// Activations transposed in LDS: XT[ch][row] (lane-contiguous -> conflict-free).
// Weights: wave-uniform scalar loads from WT[k][o].
__global__ __launch_bounds__(128) void sa1_mlp_kernel(
    const float* __restrict__ xyz, const float* __restrict__ nx1,
    const int* __restrict__ gidx,
    const float* __restrict__ W0f, const float* __restrict__ bf0,   // [64][4], [64]
    const float* __restrict__ WT1, const float* __restrict__ bf1,   // [64][64]
    const float* __restrict__ WT2, const float* __restrict__ bf2,   // [64][128]
    float* __restrict__ l1_pts) {
  __shared__ float XT[64 * 128];   // reused for X1 then X2
  int t = threadIdx.x;
  int qi = t >> 5, sm = t & 31;
  int q = blockIdx.x * 4 + qi;
  int b = q >> 9, s = q & 511;
  int idx = gidx[(size_t)q * kNS1 + sm];
  float cx = nx1[b * 1536 + s];
  float cy = nx1[b * 1536 + 512 + s];
  float cz = nx1[b * 1536 + 1024 + s];
  const float* pb = xyz + (size_t)b * 3 * kN1;
  float f0 = pb[idx] - cx, f1 = pb[kN1 + idx] - cy, f2 = pb[2 * kN1 + idx] - cz;
  // layer1: 64 outs per row
  for (int j = 0; j < 64; ++j) {
    float4 w = *(const float4*)&W0f[j * 4];
    float v = fmaf(f2, w.z, fmaf(f1, w.y, fmaf(f0, w.x, bf0[j])));
    XT[j * 128 + t] = fmaxf(v, 0.0f);
  }
  __syncthreads();
  // layer2: acc[64]
  float acc[64];
#pragma unroll
  for (int j = 0; j < 64; ++j) acc[j] = bf1[j];
  for (int k = 0; k < 64; ++k) {
    float xk = XT[k * 128 + t];
    const float* wr = WT1 + k * 64;
#pragma unroll
    for (int j = 0; j < 64; ++j) acc[j] = fmaf(xk, wr[j], acc[j]);
  }
  __syncthreads();
#pragma unroll
  for (int j = 0; j < 64; ++j) XT[j * 128 + t] = fmaxf(acc[j], 0.0f);
  __syncthreads();
  // layer3: 128 outs in 2 passes of 64, then max over 32 samples
  float* outp = l1_pts + (size_t)q * 128;
  for (int jp = 0; jp < 2; ++jp) {
#pragma unroll
    for (int j = 0; j < 64; ++j) acc[j] = bf2[jp * 64 + j];
    for (int k = 0; k < 64; ++k) {
      float xk = XT[k * 128 + t];
      const float* wr = WT2 + k * 128 + jp * 64;
#pragma unroll
      for (int j = 0; j < 64; ++j) acc[j] = fmaf(xk, wr[j], acc[j]);
    }
#pragma unroll
    for (int j = 0; j < 64; ++j) {
      float m = fmaxf(acc[j], 0.0f);
      m = fmaxf(m, __shfl_xor(m, 1, 64));
      m = fmaxf(m, __shfl_xor(m, 2, 64));
      m = fmaxf(m, __shfl_xor(m, 4, 64));
      m = fmaxf(m, __shfl_xor(m, 8, 64));
      m = fmaxf(m, __shfl_xor(m, 16, 64));
      if (sm == 0) outp[jp * 64 + j] = m;
    }
  }
}

// ---------------- SA2 grouped MLP (131->128->128->256) + max over 64 samples ----------------
// Block = 256 threads = 1 query; lane = sample, wave = output-channel group.
// f[64][133] (conflict-free b32), x1[64][129]; x2 overlays f. 32 accumulators/pass.
#define F_STR 133
#define X_STR 129
__global__ __launch_bounds__(256, 2) void sa2_mlp_kernel(
    const float* __restrict__ nx1, const float* __restrict__ l1_pts,
    const float* __restrict__ nx2, const int* __restrict__ gidx2,
    const float* __restrict__ WT1, const float* __restrict__ bf1,   // [132][128]
    const float* __restrict__ WT2, const float* __restrict__ bf2,   // [128][128]
    const float* __restrict__ WT3, const float* __restrict__ bf3,   // [128][256]
    float* __restrict__ l2_pts) {
  __shared__ float fb[64 * F_STR];    // features, later x2
  __shared__ float x1b[64 * X_STR];
  int t = threadIdx.x;
  int lane = t & 63;
  int wg = __builtin_amdgcn_readfirstlane(t >> 6);
  int q = blockIdx.x;
  int b = q >> 7, s = q & 127;
  // gather: each (lane,wg) loads 32 of the 128 l1 features for its sample
  int idx = gidx2[(size_t)q * kNS2 + lane];
  const float* pr = l1_pts + ((size_t)(b * kS1) + idx) * 128;
  float* frow = fb + lane * F_STR;
#pragma unroll
  for (int i = 0; i < 8; ++i) {
    float4 v = *(const float4*)&pr[wg * 32 + i * 4];
    frow[3 + wg * 32 + i * 4 + 0] = v.x;
    frow[3 + wg * 32 + i * 4 + 1] = v.y;
    frow[3 + wg * 32 + i * 4 + 2] = v.z;
    frow[3 + wg * 32 + i * 4 + 3] = v.w;
  }
  if (wg == 0) {
    float cx = nx2[b * 384 + s];
    float cy = nx2[b * 384 + 128 + s];
    float cz = nx2[b * 384 + 256 + s];
    frow[0] = nx1[b * 1536 + idx] - cx;
    frow[1] = nx1[b * 1536 + 512 + idx] - cy;
    frow[2] = nx1[b * 1536 + 1024 + idx] - cz;
    frow[131] = 0.0f;
  }
  __syncthreads();
  float acc[32];
  // layer1: outs j = wg*32 .. +31
#pragma unroll
  for (int j = 0; j < 32; ++j) acc[j] = bf1[wg * 32 + j];
  for (int k = 0; k < 132; ++k) {
    float xk = frow[k];
    const float* wr = WT1 + k * 128 + wg * 32;
#pragma unroll
    for (int j = 0; j < 32; ++j) acc[j] = fmaf(xk, wr[j], acc[j]);
  }
  float* xrow1 = x1b + lane * X_STR;
#pragma unroll
  for (int j = 0; j < 32; ++j) xrow1[wg * 32 + j] = fmaxf(acc[j], 0.0f);
  __syncthreads();
  // layer2
#pragma unroll
  for (int j = 0; j < 32; ++j) acc[j] = bf2[wg * 32 + j];
  for (int k = 0; k < 128; ++k) {
    float xk = xrow1[k];
    const float* wr = WT2 + k * 128 + wg * 32;
#pragma unroll
    for (int j = 0; j < 32; ++j) acc[j] = fmaf(xk, wr[j], acc[j]);
  }
  float* xrow2 = fb + lane * F_STR;   // overlay x2 on f (all f reads completed pre-barrier)
#pragma unroll
  for (int j = 0; j < 32; ++j) xrow2[wg * 32 + j] = fmaxf(acc[j], 0.0f);
  __syncthreads();
  // layer3: outs j = wg*64 .. +63, two passes of 32; max over 64 samples
  float* outp = l2_pts + (size_t)q * 256;
  for (int jp = 0; jp < 2; ++jp) {
    int j0 = wg * 64 + jp * 32;
#pragma unroll
    for (int j = 0; j < 32; ++j) acc[j] = bf3[j0 + j];
    for (int k = 0; k < 128; ++k) {
      float xk = xrow2[k];
      const float* wr = WT3 + k * 256 + j0;
#pragma unroll
      for (int j = 0; j < 32; ++j) acc[j] = fmaf(xk, wr[j], acc[j]);
    }
#pragma unroll
    for (int j = 0; j < 32; ++j) {
      float m = fmaxf(acc[j], 0.0f);
      m = fmaxf(m, __shfl_xor(m, 1, 64));
      m = fmaxf(m, __shfl_xor(m, 2, 64));
      m = fmaxf(m, __shfl_xor(m, 4, 64));
      m = fmaxf(m, __shfl_xor(m, 8, 64));
      m = fmaxf(m, __shfl_xor(m, 16, 64));
      m = fmaxf(m, __shfl_xor(m, 32, 64));
      if (lane == 0) outp[j0 + j] = m;
    }
  }
}

// ---------------- SA3 (group-all): concat -> 259->256->512->1024 -> max over 128 ----------------
__global__ void concat3_kernel(const float* __restrict__ nx2, const float* __restrict__ l2_pts,
                               float* __restrict__ F0) {
  int tot = kB * kS2 * 260;
  for (int i = blockIdx.x * blockDim.x + threadIdx.x; i < tot; i += gridDim.x * blockDim.x) {
    int row = i / 260, k = i - row * 260;
    int b = row >> 7, s = row & 127;
    float v;
    if (k < 3) v = nx2[(size_t)b * 3 * kS2 + k * kS2 + s];
    else if (k < 259) v = l2_pts[(size_t)row * 256 + (k - 3)];
    else v = 0.0f;
    F0[i] = v;
  }
}

template <int KP>
__global__ __launch_bounds__(256, 2) void mlp_pass_kernel(
    const float* __restrict__ X, const float* __restrict__ WT, const float* __restrict__ bf,
    int O, float* __restrict__ Y) {
  __shared__ float sF[16 * KP];
  int stile = blockIdx.x, t = threadIdx.x;
  int j = blockIdx.y * 256 + t;
  const float* xb = X + (size_t)stile * 16 * KP;
  for (int i = t; i < 16 * KP; i += 256) sF[i] = xb[i];
  __syncthreads();
  float acc[16];
  float bj = bf[j];
#pragma unroll
  for (int s = 0; s < 16; ++s) acc[s] = bj;
  for (int k = 0; k < KP; k += 4) {
    float w0 = WT[(size_t)k * O + j];
    float w1 = WT[(size_t)(k + 1) * O + j];
    float w2 = WT[(size_t)(k + 2) * O + j];
    float w3 = WT[(size_t)(k + 3) * O + j];
#pragma unroll
    for (int s = 0; s < 16; ++s) {
      const float4 fv = *(const float4*)&sF[s * KP + k];
      acc[s] = fmaf(fv.x, w0, acc[s]);
      acc[s] = fmaf(fv.y, w1, acc[s]);
      acc[s] = fmaf(fv.z, w2, acc[s]);
      acc[s] = fmaf(fv.w, w3, acc[s]);
    }
  }
  float* yb = Y + (size_t)stile * 16 * O + j;
#pragma unroll
  for (int s = 0; s < 16; ++s) yb[(size_t)s * O] = fmaxf(acc[s], 0.0f);
}

__global__ __launch_bounds__(256, 2) void sa3_final_kernel(
    const float* __restrict__ X2g, const float* __restrict__ WTc, const float* __restrict__ bfc,
    float* __restrict__ out) {
  __shared__ float sF[16 * 512];
  int b = blockIdx.x, t = threadIdx.x;
  int j = blockIdx.y * 256 + t;
  float m = 0.0f;
  float bj = bfc[j];
  for (int st = 0; st < 8; ++st) {
    const float* xb = X2g + ((size_t)b * 128 + st * 16) * 512;
    for (int i = t; i < 16 * 512; i += 256) sF[i] = xb[i];
    __syncthreads();
    float acc[16];
#pragma unroll
    for (int s = 0; s < 16; ++s) acc[s] = bj;
    for (int k = 0; k < 512; k += 4) {
      float w0 = WTc[(size_t)k * 1024 + j];
      float w1 = WTc[(size_t)(k + 1) * 1024 + j];
      float w2 = WTc[(size_t)(k + 2) * 1024 + j];
      float w3 = WTc[(size_t)(k + 3) * 1024 + j];
#pragma unroll
      for (int s = 0; s < 16; ++s) {
        const float4 fv = *(const float4*)&sF[s * 512 + k];
        acc[s] = fmaf(fv.x, w0, acc[s]);
        acc[s] = fmaf(fv.y, w1, acc[s]);
        acc[s] = fmaf(fv.z, w2, acc[s]);
        acc[s] = fmaf(fv.w, w3, acc[s]);
      }
    }
#pragma unroll
    for (int s = 0; s < 16; ++s) m = fmaxf(m, fmaxf(acc[s], 0.0f));
    __syncthreads();
  }
  out[(size_t)b * 1024 + j] = m;
}

// ---------------- launch ----------------
extern "C" void kernel_launch(void* const* d_in, const int* in_sizes, int n_in,
                              void* d_out, int out_size, void* d_ws, size_t ws_size,
                              hipStream_t stream) {
  (void)in_sizes; (void)n_in; (void)out_size; (void)ws_size;
  const float* xyz = (const float*)d_in[0];
  auto WP = [&](int layer, int part) -> const float* {
    return (const float*)d_in[1 + layer * 4 + part];
  };
  float* wsf = (float*)d_ws;
  size_t cur = 0;
  auto alloc = [&](size_t n) { size_t o = cur; cur += (n + 63) & ~(size_t)63; return o; };
  size_t o_nx1 = alloc((size_t)kB * 3 * kS1);
  size_t o_nx2 = alloc((size_t)kB * 3 * kS2);
  size_t o_l1pts = alloc((size_t)kB * kS1 * 128);
  size_t o_l2pts = alloc((size_t)kB * kS2 * 256);
  size_t o_F0 = alloc((size_t)kB * kS2 * 260);
  size_t o_X1g = alloc((size_t)kB * kS2 * 256);
  size_t o_X2g = alloc((size_t)kB * kS2 * 512);
  size_t o_s1w0 = alloc(64 * 4), o_s1b0 = alloc(64);
  size_t o_s1w1 = alloc(64 * 64), o_s1b1 = alloc(64);
  size_t o_s1wt2 = alloc(64 * 128), o_s1b2 = alloc(128);
  size_t o_s2w1 = alloc(132 * 128), o_s2b1 = alloc(128);
  size_t o_s2wt2 = alloc(128 * 128), o_s2b2 = alloc(128);
  size_t o_s2w3 = alloc(128 * 256), o_s2b3 = alloc(256);
  size_t o_s3wtA = alloc(260 * 256), o_s3bA = alloc(256);
  size_t o_s3wtB = alloc(256 * 512), o_s3bB = alloc(512);
  size_t o_s3wtC = alloc(512 * 1024), o_s3bC = alloc(1024);
  size_t o_gidx1 = alloc((size_t)kB * kS1 * kNS1);
  size_t o_gidx2 = alloc((size_t)kB * kS2 * kNS2);
  int* gidx1 = (int*)(wsf + o_gidx1);
  int* gidx2 = (int*)(wsf + o_gidx2);

  // fold all 9 layers
  fold_kernel<<<64, 256, 0, stream>>>(WP(0, 0), WP(0, 1), WP(0, 2), WP(0, 3), 64, 3, 4,
                                      wsf + o_s1w0, (float*)nullptr, wsf + o_s1b0);
  fold_kernel<<<64, 256, 0, stream>>>(WP(1, 0), WP(1, 1), WP(1, 2), WP(1, 3), 64, 64, 64,
                                      (float*)nullptr, wsf + o_s1w1, wsf + o_s1b1);
  fold_kernel<<<64, 256, 0, stream>>>(WP(2, 0), WP(2, 1), WP(2, 2), WP(2, 3), 128, 64, 64,
                                      (float*)nullptr, wsf + o_s1wt2, wsf + o_s1b2);
  fold_kernel<<<128, 256, 0, stream>>>(WP(3, 0), WP(3, 1), WP(3, 2), WP(3, 3), 128, 131, 132,
                                       (float*)nullptr, wsf + o_s2w1, wsf + o_s2b1);
  fold_kernel<<<128, 256, 0, stream>>>(WP(4, 0), WP(4, 1), WP(4, 2), WP(4, 3), 128, 128, 128,
                                       (float*)nullptr, wsf + o_s2wt2, wsf + o_s2b2);
  fold_kernel<<<128, 256, 0, stream>>>(WP(5, 0), WP(5, 1), WP(5, 2), WP(5, 3), 256, 128, 128,
                                       (float*)nullptr, wsf + o_s2w3, wsf + o_s2b3);
  fold_kernel<<<256, 256, 0, stream>>>(WP(6, 0), WP(6, 1), WP(6, 2), WP(6, 3), 256, 259, 260,
                                       (float*)nullptr, wsf + o_s3wtA, wsf + o_s3bA);
  fold_kernel<<<256, 256, 0, stream>>>(WP(7, 0), WP(7, 1), WP(7, 2), WP(7, 3), 512, 256, 256,
                                       (float*)nullptr, wsf + o_s3wtB, wsf + o_s3bB);
  fold_kernel<<<512, 256, 0, stream>>>(WP(8, 0), WP(8, 1), WP(8, 2), WP(8, 3), 1024, 512, 512,
                                       (float*)nullptr, wsf + o_s3wtC, wsf + o_s3bC);

  // SA1
  fps_kernel<kN1, kS1, 512><<<kB, 512, 0, stream>>>(xyz, wsf + o_nx1);
  bq_kernel<kN1, kS1, kNS1><<<(kB * kS1) / 4, 256, 0, stream>>>(xyz, wsf + o_nx1, 0.04f, gidx1);
  sa1_mlp_kernel<<<(kB * kS1) / 4, 128, 0, stream>>>(
      xyz, wsf + o_nx1, gidx1,
      wsf + o_s1w0, wsf + o_s1b0, wsf + o_s1w1, wsf + o_s1b1, wsf + o_s1wt2, wsf + o_s1b2,
      wsf + o_l1pts);

  // SA2
  fps_kernel<kS1, kS2, 128><<<kB, 128, 0, stream>>>(wsf + o_nx1, wsf + o_nx2);
  bq_kernel<kS1, kS2, kNS2><<<(kB * kS2) / 4, 256, 0, stream>>>(wsf + o_nx1, wsf + o_nx2, 0.16f, gidx2);
  sa2_mlp_kernel<<<kB * kS2, 256, 0, stream>>>(
      wsf + o_nx1, wsf + o_l1pts, wsf + o_nx2, gidx2,
      wsf + o_s2w1, wsf + o_s2b1, wsf + o_s2wt2, wsf + o_s2b2, wsf + o_s2w3, wsf + o_s2b3,
      wsf + o_l2pts);

  // SA3 (group all)
  concat3_kernel<<<1024, 256, 0, stream>>>(wsf + o_nx2, wsf + o_l2pts, wsf + o_F0);
  mlp_pass_kernel<260><<<dim3(256, 1), 256, 0, stream>>>(wsf + o_F0, wsf + o_s3wtA, wsf + o_s3bA, 256, wsf + o_X1g);
  mlp_pass_kernel<256><<<dim3(256, 2), 256, 0, stream>>>(wsf + o_X1g, wsf + o_s3wtB, wsf + o_s3bB, 512, wsf + o_X2g);
  sa3_final_kernel<<<dim3(kB, 4), 256, 0, stream>>>(wsf + o_X2g, wsf + o_s3wtC, wsf + o_s3bC, (float*)d_out);
}

// Round 3
// 1713.120 us; speedup vs baseline: 2.3796x; 1.2838x over previous
//
#include <hip/hip_runtime.h>
#include <hip/hip_bf16.h>
#include <cstddef>
#include <math.h>

#define kB 32
#define kN1 4096
#define kS1 512
#define kNS1 32
#define kS2 128
#define kNS2 64

// ---------------- weight folding: W' = W * g/sqrt(1+eps), b' = b*g/sqrt(1+eps) + bt ----------
__global__ void fold_kernel(const float* __restrict__ W, const float* __restrict__ bias,
                            const float* __restrict__ g, const float* __restrict__ bt,
                            int O, int K, int Kp,
                            float* __restrict__ Wf, float* __restrict__ WT,
                            float* __restrict__ bf) {
  float inv = 1.0f / sqrtf(1.0f + 1e-5f);
  int stride = gridDim.x * blockDim.x;
  int tid = blockIdx.x * blockDim.x + threadIdx.x;
  for (int i = tid; i < O * Kp; i += stride) {
    int o = i / Kp, k = i - o * Kp;
    float s = g[o] * inv;
    float w = (k < K) ? W[o * K + k] * s : 0.0f;
    if (Wf) Wf[o * Kp + k] = w;
    if (WT) WT[k * O + o] = w;
  }
  for (int o = tid; o < O; o += stride) {
    bf[o] = bias[o] * (g[o] * inv) + bt[o];
  }
}

// ---------------- farthest point sampling (register-resident, 1 barrier/iter) ----------------
// Coords in registers (R per thread). Argmax via packed u64 key = (dist_bits<<32) | ~idx
// (unique keys -> exact first-max tie-break). Winner lane publishes next centroid coords.
// Parity ping-pong on skey/scoord -> single __syncthreads per iteration.
template <int N, int NP, int T>
__global__ __launch_bounds__(T) void fps_kernel(const float* __restrict__ xyz,  // (B,3,N)
                                                float* __restrict__ nx) {       // (B,3,NP)
  constexpr int W = T / 64;
  constexpr int R = N / T;
  __shared__ unsigned long long skey[2][W];
  __shared__ float scoord[2][W][3];
  __shared__ int fid[NP];
  int b = blockIdx.x, t = threadIdx.x;
  int w = t >> 6;
  const float* base = xyz + (size_t)b * 3 * N;
  float px[R], py[R], pz[R], dd[R];
#pragma unroll
  for (int r = 0; r < R; ++r) {
    int i = t + r * T;
    px[r] = base[i];
    py[r] = base[N + i];
    pz[r] = base[2 * N + i];
    dd[r] = 1e10f;
  }
  if (t < W) skey[0][t] = (t == 0) ? ~0ull : 0ull;   // slot 0 wins; decodes to idx 0
  if (t == 0) {
    fid[0] = 0;
    scoord[0][0][0] = px[0];  // thread 0 owns point 0
    scoord[0][0][1] = py[0];
    scoord[0][0][2] = pz[0];
  }
  int par = 0;
  __syncthreads();
  for (int it = 1; it < NP; ++it) {
    // block winner from previous iteration (broadcast reads)
    unsigned long long m = skey[par][0];
    int ws = 0;
#pragma unroll
    for (int w2 = 1; w2 < W; ++w2) {
      unsigned long long v = skey[par][w2];
      if (v > m) { m = v; ws = w2; }
    }
    float cx = scoord[par][ws][0], cy = scoord[par][ws][1], cz = scoord[par][ws][2];
    if (t == 0) fid[it - 1] = (int)(~(unsigned)m);
    // update min-dists, track local best (key + candidate coords)
    unsigned long long lbest = 0;
    float bx = px[0], by = py[0], bz = pz[0];
#pragma unroll
    for (int r = 0; r < R; ++r) {
      float dx = __fsub_rn(px[r], cx);
      float dy = __fsub_rn(py[r], cy);
      float dz = __fsub_rn(pz[r], cz);
      float d = fmaf(dz, dz, fmaf(dy, dy, __fmul_rn(dx, dx)));
      float nd = fminf(dd[r], d);
      dd[r] = nd;
      unsigned long long kb =
          ((unsigned long long)__float_as_uint(nd) << 32) | (unsigned)(~(t + r * T));
      if (kb > lbest) { lbest = kb; bx = px[r]; by = py[r]; bz = pz[r]; }
    }
    // wave-wide unsigned max
    unsigned long long wbest = lbest;
#pragma unroll
    for (int off = 32; off >= 1; off >>= 1) {
      unsigned long long o = __shfl_xor(wbest, off, 64);
      if (o > wbest) wbest = o;
    }
    // unique winner lane publishes
    if (lbest == wbest) {
      skey[par ^ 1][w] = wbest;
      scoord[par ^ 1][w][0] = bx;
      scoord[par ^ 1][w][1] = by;
      scoord[par ^ 1][w][2] = bz;
    }
    __syncthreads();
    par ^= 1;
  }
  // final selection
  {
    unsigned long long m = skey[par][0];
#pragma unroll
    for (int w2 = 1; w2 < W; ++w2) {
      unsigned long long v = skey[par][w2];
      if (v > m) m = v;
    }
    if (t == 0) fid[NP - 1] = (int)(~(unsigned)m);
  }
  __syncthreads();
  for (int s = t; s < NP; s += T) {
    int f = fid[s];
    nx[(size_t)b * 3 * NP + s] = base[f];
    nx[(size_t)b * 3 * NP + NP + s] = base[N + f];
    nx[(size_t)b * 3 * NP + 2 * NP + s] = base[2 * N + f];
  }
}

// ---------------- ball query ----------------
template <int NPTS, int NQ, int NS>
__global__ void bq_kernel(const float* __restrict__ pts, const float* __restrict__ qry,
                          float r2, int* __restrict__ gidx) {
  int gw = (blockIdx.x * blockDim.x + threadIdx.x) >> 6;
  int lane = threadIdx.x & 63;
  if (gw >= kB * NQ) return;
  int b = gw / NQ, s = gw - b * NQ;
  const float* pb = pts + (size_t)b * 3 * NPTS;
  float cx = qry[(size_t)b * 3 * NQ + s];
  float cy = qry[(size_t)b * 3 * NQ + NQ + s];
  float cz = qry[(size_t)b * 3 * NQ + 2 * NQ + s];
  float ss = fmaf(cz, cz, fmaf(cy, cy, __fmul_rn(cx, cx)));
  int* out = gidx + (size_t)gw * NS;
  int have = 0, first = 0;
  bool gotfirst = false;
  for (int n0 = 0; n0 < NPTS; n0 += 64) {
    int n = n0 + lane;
    float x = pb[n], y = pb[NPTS + n], z = pb[2 * NPTS + n];
    float dd = fmaf(z, z, fmaf(y, y, __fmul_rn(x, x)));
    float cross = fmaf(cz, z, fmaf(cy, y, __fmul_rn(cx, x)));
    float sqr = __fsub_rn(__fadd_rn(ss, dd), __fmul_rn(2.0f, cross));
    bool pred = !(sqr > r2);
    unsigned long long mask = __ballot(pred);
    if (!gotfirst && mask) { first = n0 + (__ffsll(mask) - 1); gotfirst = true; }
    if (pred) {
      int pos = have + __popcll(mask & ((1ull << lane) - 1ull));
      if (pos < NS) out[pos] = n;
    }
    have += __popcll(mask);
    if (have >= NS) break;
  }
  for (int slot = have + lane; slot < NS; slot += 64) out[slot] = first;
}

// ---------------- SA1 grouped MLP (3->64->64->128) + max over 32 samples ----------------
// Block = 256 threads = 8 queries x 32 samples; thread owns one row.
// Activations transposed in LDS: XT[ch][row] (64KB -> 2 blocks/CU).
__global__ __launch_bounds__(256, 4) void sa1_mlp_kernel(
    const float* __restrict__ xyz, const float* __restrict__ nx1,
    const int* __restrict__ gidx,
    const float* __restrict__ W0f, const float* __restrict__ bf0,   // [64][4], [64]
    const float* __restrict__ WT1, const float* __restrict__ bf1,   // [64][64]
    const float* __restrict__ WT2, const float* __restrict__ bf2,   // [64][128]
    float* __restrict__ l1_pts) {
  __shared__ float XT[64 * 256];   // reused for X1 then X2
  int t = threadIdx.x;
  int qi = t >> 5, sm = t & 31;
  int q = blockIdx.x * 8 + qi;
  int b = q >> 9, s = q & 511;
  int idx = gidx[(size_t)q * kNS1 + sm];
  float cx = nx1[b * 1536 + s];
  float cy = nx1[b * 1536 + 512 + s];
  float cz = nx1[b * 1536 + 1024 + s];
  const float* pb = xyz + (size_t)b * 3 * kN1;
  float f0 = pb[idx] - cx, f1 = pb[kN1 + idx] - cy, f2 = pb[2 * kN1 + idx] - cz;
  // layer1: 64 outs per row
  for (int j = 0; j < 64; ++j) {
    float4 w = *(const float4*)&W0f[j * 4];
    float v = fmaf(f2, w.z, fmaf(f1, w.y, fmaf(f0, w.x, bf0[j])));
    XT[j * 256 + t] = fmaxf(v, 0.0f);
  }
  __syncthreads();
  // layer2: acc[64]
  float acc[64];
#pragma unroll
  for (int j = 0; j < 64; ++j) acc[j] = bf1[j];
  for (int k = 0; k < 64; ++k) {
    float xk = XT[k * 256 + t];
    const float* wr = WT1 + k * 64;
#pragma unroll
    for (int j = 0; j < 64; ++j) acc[j] = fmaf(xk, wr[j], acc[j]);
  }
  __syncthreads();
#pragma unroll
  for (int j = 0; j < 64; ++j) XT[j * 256 + t] = fmaxf(acc[j], 0.0f);
  __syncthreads();
  // layer3: 128 outs in 2 passes of 64, then max over 32 samples
  float* outp = l1_pts + (size_t)q * 128;
  for (int jp = 0; jp < 2; ++jp) {
#pragma unroll
    for (int j = 0; j < 64; ++j) acc[j] = bf2[jp * 64 + j];
    for (int k = 0; k < 64; ++k) {
      float xk = XT[k * 256 + t];
      const float* wr = WT2 + k * 128 + jp * 64;
#pragma unroll
      for (int j = 0; j < 64; ++j) acc[j] = fmaf(xk, wr[j], acc[j]);
    }
#pragma unroll
    for (int j = 0; j < 64; ++j) {
      float m = fmaxf(acc[j], 0.0f);
      m = fmaxf(m, __shfl_xor(m, 1, 64));
      m = fmaxf(m, __shfl_xor(m, 2, 64));
      m = fmaxf(m, __shfl_xor(m, 4, 64));
      m = fmaxf(m, __shfl_xor(m, 8, 64));
      m = fmaxf(m, __shfl_xor(m, 16, 64));
      if (sm == 0) outp[jp * 64 + j] = m;
    }
  }
}

// ---------------- SA2 grouped MLP (131->128->128->256) + max over 64 samples ----------------
// Block = 256 threads = 1 query; lane = sample, wave = output-channel group.
// Single LDS buffer fb[64][133] (34KB -> 4 blocks/CU): x1/x2 written back into f
// region after barriers (f fully consumed by end of layer1).
#define F_STR 133
__global__ __launch_bounds__(256, 4) void sa2_mlp_kernel(
    const float* __restrict__ nx1, const float* __restrict__ l1_pts,
    const float* __restrict__ nx2, const int* __restrict__ gidx2,
    const float* __restrict__ WT1, const float* __restrict__ bf1,   // [132][128]
    const float* __restrict__ WT2, const float* __restrict__ bf2,   // [128][128]
    const float* __restrict__ WT3, const float* __restrict__ bf3,   // [128][256]
    float* __restrict__ l2_pts) {
  __shared__ float fb[64 * F_STR];
  int t = threadIdx.x;
  int lane = t & 63;
  int wg = __builtin_amdgcn_readfirstlane(t >> 6);
  int q = blockIdx.x;
  int b = q >> 7, s = q & 127;
  // gather: each (lane,wg) loads 32 of the 128 l1 features for its sample
  int idx = gidx2[(size_t)q * kNS2 + lane];
  const float* pr = l1_pts + ((size_t)(b * kS1) + idx) * 128;
  float* frow = fb + lane * F_STR;
#pragma unroll
  for (int i = 0; i < 8; ++i) {
    float4 v = *(const float4*)&pr[wg * 32 + i * 4];
    frow[3 + wg * 32 + i * 4 + 0] = v.x;
    frow[3 + wg * 32 + i * 4 + 1] = v.y;
    frow[3 + wg * 32 + i * 4 + 2] = v.z;
    frow[3 + wg * 32 + i * 4 + 3] = v.w;
  }
  if (wg == 0) {
    float cx = nx2[b * 384 + s];
    float cy = nx2[b * 384 + 128 + s];
    float cz = nx2[b * 384 + 256 + s];
    frow[0] = nx1[b * 1536 + idx] - cx;
    frow[1] = nx1[b * 1536 + 512 + idx] - cy;
    frow[2] = nx1[b * 1536 + 1024 + idx] - cz;
    frow[131] = 0.0f;
  }
  __syncthreads();
  float acc[32];
  // layer1: outs j = wg*32 .. +31
#pragma unroll
  for (int j = 0; j < 32; ++j) acc[j] = bf1[wg * 32 + j];
  for (int k = 0; k < 132; ++k) {
    float xk = frow[k];
    const float* wr = WT1 + k * 128 + wg * 32;
#pragma unroll
    for (int j = 0; j < 32; ++j) acc[j] = fmaf(xk, wr[j], acc[j]);
  }
  __syncthreads();   // all reads of f complete
#pragma unroll
  for (int j = 0; j < 32; ++j) frow[wg * 32 + j] = fmaxf(acc[j], 0.0f);
  __syncthreads();
  // layer2
#pragma unroll
  for (int j = 0; j < 32; ++j) acc[j] = bf2[wg * 32 + j];
  for (int k = 0; k < 128; ++k) {
    float xk = frow[k];
    const float* wr = WT2 + k * 128 + wg * 32;
#pragma unroll
    for (int j = 0; j < 32; ++j) acc[j] = fmaf(xk, wr[j], acc[j]);
  }
  __syncthreads();   // all reads of x1 complete
#pragma unroll
  for (int j = 0; j < 32; ++j) frow[wg * 32 + j] = fmaxf(acc[j], 0.0f);
  __syncthreads();
  // layer3: outs j = wg*64 .. +63, two passes of 32; max over 64 samples
  float* outp = l2_pts + (size_t)q * 256;
  for (int jp = 0; jp < 2; ++jp) {
    int j0 = wg * 64 + jp * 32;
#pragma unroll
    for (int j = 0; j < 32; ++j) acc[j] = bf3[j0 + j];
    for (int k = 0; k < 128; ++k) {
      float xk = frow[k];
      const float* wr = WT3 + k * 256 + j0;
#pragma unroll
      for (int j = 0; j < 32; ++j) acc[j] = fmaf(xk, wr[j], acc[j]);
    }
#pragma unroll
    for (int j = 0; j < 32; ++j) {
      float m = fmaxf(acc[j], 0.0f);
      m = fmaxf(m, __shfl_xor(m, 1, 64));
      m = fmaxf(m, __shfl_xor(m, 2, 64));
      m = fmaxf(m, __shfl_xor(m, 4, 64));
      m = fmaxf(m, __shfl_xor(m, 8, 64));
      m = fmaxf(m, __shfl_xor(m, 16, 64));
      m = fmaxf(m, __shfl_xor(m, 32, 64));
      if (lane == 0) outp[j0 + j] = m;
    }
  }
}

// ---------------- SA3 (group-all): concat -> 259->256->512->1024 -> max over 128 ----------------
__global__ void concat3_kernel(const float* __restrict__ nx2, const float* __restrict__ l2_pts,
                               float* __restrict__ F0) {
  int tot = kB * kS2 * 260;
  for (int i = blockIdx.x * blockDim.x + threadIdx.x; i < tot; i += gridDim.x * blockDim.x) {
    int row = i / 260, k = i - row * 260;
    int b = row >> 7, s = row & 127;
    float v;
    if (k < 3) v = nx2[(size_t)b * 3 * kS2 + k * kS2 + s];
    else if (k < 259) v = l2_pts[(size_t)row * 256 + (k - 3)];
    else v = 0.0f;
    F0[i] = v;
  }
}

template <int KP>
__global__ __launch_bounds__(256, 2) void mlp_pass_kernel(
    const float* __restrict__ X, const float* __restrict__ WT, const float* __restrict__ bf,
    int O, float* __restrict__ Y) {
  __shared__ float sF[16 * KP];
  int stile = blockIdx.x, t = threadIdx.x;
  int j = blockIdx.y * 256 + t;
  const float* xb = X + (size_t)stile * 16 * KP;
  for (int i = t; i < 16 * KP; i += 256) sF[i] = xb[i];
  __syncthreads();
  float acc[16];
  float bj = bf[j];
#pragma unroll
  for (int s = 0; s < 16; ++s) acc[s] = bj;
  for (int k = 0; k < KP; k += 4) {
    float w0 = WT[(size_t)k * O + j];
    float w1 = WT[(size_t)(k + 1) * O + j];
    float w2 = WT[(size_t)(k + 2) * O + j];
    float w3 = WT[(size_t)(k + 3) * O + j];
#pragma unroll
    for (int s = 0; s < 16; ++s) {
      const float4 fv = *(const float4*)&sF[s * KP + k];
      acc[s] = fmaf(fv.x, w0, acc[s]);
      acc[s] = fmaf(fv.y, w1, acc[s]);
      acc[s] = fmaf(fv.z, w2, acc[s]);
      acc[s] = fmaf(fv.w, w3, acc[s]);
    }
  }
  float* yb = Y + (size_t)stile * 16 * O + j;
#pragma unroll
  for (int s = 0; s < 16; ++s) yb[(size_t)s * O] = fmaxf(acc[s], 0.0f);
}

__global__ __launch_bounds__(256, 2) void sa3_final_kernel(
    const float* __restrict__ X2g, const float* __restrict__ WTc, const float* __restrict__ bfc,
    float* __restrict__ out) {
  __shared__ float sF[16 * 512];
  int b = blockIdx.x, t = threadIdx.x;
  int j = blockIdx.y * 256 + t;
  float m = 0.0f;
  float bj = bfc[j];
  for (int st = 0; st < 8; ++st) {
    const float* xb = X2g + ((size_t)b * 128 + st * 16) * 512;
    for (int i = t; i < 16 * 512; i += 256) sF[i] = xb[i];
    __syncthreads();
    float acc[16];
#pragma unroll
    for (int s = 0; s < 16; ++s) acc[s] = bj;
    for (int k = 0; k < 512; k += 4) {
      float w0 = WTc[(size_t)k * 1024 + j];
      float w1 = WTc[(size_t)(k + 1) * 1024 + j];
      float w2 = WTc[(size_t)(k + 2) * 1024 + j];
      float w3 = WTc[(size_t)(k + 3) * 1024 + j];
#pragma unroll
      for (int s = 0; s < 16; ++s) {
        const float4 fv = *(const float4*)&sF[s * 512 + k];
        acc[s] = fmaf(fv.x, w0, acc[s]);
        acc[s] = fmaf(fv.y, w1, acc[s]);
        acc[s] = fmaf(fv.z, w2, acc[s]);
        acc[s] = fmaf(fv.w, w3, acc[s]);
      }
    }
#pragma unroll
    for (int s = 0; s < 16; ++s) m = fmaxf(m, fmaxf(acc[s], 0.0f));
    __syncthreads();
  }
  out[(size_t)b * 1024 + j] = m;
}

// ---------------- launch ----------------
extern "C" void kernel_launch(void* const* d_in, const int* in_sizes, int n_in,
                              void* d_out, int out_size, void* d_ws, size_t ws_size,
                              hipStream_t stream) {
  (void)in_sizes; (void)n_in; (void)out_size; (void)ws_size;
  const float* xyz = (const float*)d_in[0];
  auto WP = [&](int layer, int part) -> const float* {
    return (const float*)d_in[1 + layer * 4 + part];
  };
  float* wsf = (float*)d_ws;
  size_t cur = 0;
  auto alloc = [&](size_t n) { size_t o = cur; cur += (n + 63) & ~(size_t)63; return o; };
  size_t o_nx1 = alloc((size_t)kB * 3 * kS1);
  size_t o_nx2 = alloc((size_t)kB * 3 * kS2);
  size_t o_l1pts = alloc((size_t)kB * kS1 * 128);
  size_t o_l2pts = alloc((size_t)kB * kS2 * 256);
  size_t o_F0 = alloc((size_t)kB * kS2 * 260);
  size_t o_X1g = alloc((size_t)kB * kS2 * 256);
  size_t o_X2g = alloc((size_t)kB * kS2 * 512);
  size_t o_s1w0 = alloc(64 * 4), o_s1b0 = alloc(64);
  size_t o_s1w1 = alloc(64 * 64), o_s1b1 = alloc(64);
  size_t o_s1wt2 = alloc(64 * 128), o_s1b2 = alloc(128);
  size_t o_s2w1 = alloc(132 * 128), o_s2b1 = alloc(128);
  size_t o_s2wt2 = alloc(128 * 128), o_s2b2 = alloc(128);
  size_t o_s2w3 = alloc(128 * 256), o_s2b3 = alloc(256);
  size_t o_s3wtA = alloc(260 * 256), o_s3bA = alloc(256);
  size_t o_s3wtB = alloc(256 * 512), o_s3bB = alloc(512);
  size_t o_s3wtC = alloc(512 * 1024), o_s3bC = alloc(1024);
  size_t o_gidx1 = alloc((size_t)kB * kS1 * kNS1);
  size_t o_gidx2 = alloc((size_t)kB * kS2 * kNS2);
  int* gidx1 = (int*)(wsf + o_gidx1);
  int* gidx2 = (int*)(wsf + o_gidx2);

  // fold all 9 layers
  fold_kernel<<<64, 256, 0, stream>>>(WP(0, 0), WP(0, 1), WP(0, 2), WP(0, 3), 64, 3, 4,
                                      wsf + o_s1w0, (float*)nullptr, wsf + o_s1b0);
  fold_kernel<<<64, 256, 0, stream>>>(WP(1, 0), WP(1, 1), WP(1, 2), WP(1, 3), 64, 64, 64,
                                      (float*)nullptr, wsf + o_s1w1, wsf + o_s1b1);
  fold_kernel<<<64, 256, 0, stream>>>(WP(2, 0), WP(2, 1), WP(2, 2), WP(2, 3), 128, 64, 64,
                                      (float*)nullptr, wsf + o_s1wt2, wsf + o_s1b2);
  fold_kernel<<<128, 256, 0, stream>>>(WP(3, 0), WP(3, 1), WP(3, 2), WP(3, 3), 128, 131, 132,
                                       (float*)nullptr, wsf + o_s2w1, wsf + o_s2b1);
  fold_kernel<<<128, 256, 0, stream>>>(WP(4, 0), WP(4, 1), WP(4, 2), WP(4, 3), 128, 128, 128,
                                       (float*)nullptr, wsf + o_s2wt2, wsf + o_s2b2);
  fold_kernel<<<128, 256, 0, stream>>>(WP(5, 0), WP(5, 1), WP(5, 2), WP(5, 3), 256, 128, 128,
                                       (float*)nullptr, wsf + o_s2w3, wsf + o_s2b3);
  fold_kernel<<<256, 256, 0, stream>>>(WP(6, 0), WP(6, 1), WP(6, 2), WP(6, 3), 256, 259, 260,
                                       (float*)nullptr, wsf + o_s3wtA, wsf + o_s3bA);
  fold_kernel<<<256, 256, 0, stream>>>(WP(7, 0), WP(7, 1), WP(7, 2), WP(7, 3), 512, 256, 256,
                                       (float*)nullptr, wsf + o_s3wtB, wsf + o_s3bB);
  fold_kernel<<<512, 256, 0, stream>>>(WP(8, 0), WP(8, 1), WP(8, 2), WP(8, 3), 1024, 512, 512,
                                       (float*)nullptr, wsf + o_s3wtC, wsf + o_s3bC);

  // SA1
  fps_kernel<kN1, kS1, 256><<<kB, 256, 0, stream>>>(xyz, wsf + o_nx1);
  bq_kernel<kN1, kS1, kNS1><<<(kB * kS1) / 4, 256, 0, stream>>>(xyz, wsf + o_nx1, 0.04f, gidx1);
  sa1_mlp_kernel<<<(kB * kS1) / 8, 256, 0, stream>>>(
      xyz, wsf + o_nx1, gidx1,
      wsf + o_s1w0, wsf + o_s1b0, wsf + o_s1w1, wsf + o_s1b1, wsf + o_s1wt2, wsf + o_s1b2,
      wsf + o_l1pts);

  // SA2
  fps_kernel<kS1, kS2, 64><<<kB, 64, 0, stream>>>(wsf + o_nx1, wsf + o_nx2);
  bq_kernel<kS1, kS2, kNS2><<<(kB * kS2) / 4, 256, 0, stream>>>(wsf + o_nx1, wsf + o_nx2, 0.16f, gidx2);
  sa2_mlp_kernel<<<kB * kS2, 256, 0, stream>>>(
      wsf + o_nx1, wsf + o_l1pts, wsf + o_nx2, gidx2,
      wsf + o_s2w1, wsf + o_s2b1, wsf + o_s2wt2, wsf + o_s2b2, wsf + o_s2w3, wsf + o_s2b3,
      wsf + o_l2pts);

  // SA3 (group all)
  concat3_kernel<<<1024, 256, 0, stream>>>(wsf + o_nx2, wsf + o_l2pts, wsf + o_F0);
  mlp_pass_kernel<260><<<dim3(256, 1), 256, 0, stream>>>(wsf + o_F0, wsf + o_s3wtA, wsf + o_s3bA, 256, wsf + o_X1g);
  mlp_pass_kernel<256><<<dim3(256, 2), 256, 0, stream>>>(wsf + o_X1g, wsf + o_s3wtB, wsf + o_s3bB, 512, wsf + o_X2g);
  sa3_final_kernel<<<dim3(kB, 4), 256, 0, stream>>>(wsf + o_X2g, wsf + o_s3wtC, wsf + o_s3bC, (float*)d_out);
}